// Round 6
// baseline (300.878 us; speedup 1.0000x reference)
//
#include <hip/hip_runtime.h>
#include <hip/hip_bf16.h>

// ---------------------------------------------------------------------------
// BehaviorSpecificPFF: token-routed 4-expert FFN.
//   y[tok] = relu(x[tok] @ W1[g] + B1[g]) @ W2[g] + B2[g],  g = b_seq[tok]-1
//   b_seq==0 -> zeros.
// Round 6: 256-wide tiles (GEMM1 256x256, GEMM2 256x128), BK=32, chunk-major
// LDS layout [kchunk][row][16B] -> linear global_load_lds dests AND
// conflict-free fragment reads with no swizzle. r5-proven 2-phase skeleton
// unchanged. Bijective XCD swizzle for L2 locality.
// ---------------------------------------------------------------------------

typedef short s16x8 __attribute__((ext_vector_type(8)));
typedef float f32x4 __attribute__((ext_vector_type(4)));

#define NTOK   16384
#define HDIM   512
#define FDIM   2048
#define NEXP   4

// ---- header layout (ints) in ws ----
// [0..3] counts  [4..7] cursors  [8..12] token offsets ([12]=total)
// [13..17] gemm1 tile bases ([17]=total)  [18..22] gemm2 tile bases

__global__ void k_init_cvt(const float* __restrict__ x,
                           const int* __restrict__ b_seq,
                           __hip_bfloat16* __restrict__ xb,
                           float4* __restrict__ out, int n4,
                           int* __restrict__ hdr, float4* __restrict__ zp) {
  if (blockIdx.x == 0 && threadIdx.x < 32) hdr[threadIdx.x] = 0;
  float4 z; z.x = z.y = z.z = z.w = 0.f;
  int zb = (int)blockIdx.x - 1;
  if (zb >= 0 && zb < 2) zp[zb * 256 + threadIdx.x] = z;  // 8KB zero slab
  union { __hip_bfloat16 b[4]; uint2 u; } t;
  for (int i = blockIdx.x * blockDim.x + threadIdx.x; i < n4;
       i += gridDim.x * blockDim.x) {
    // non-pad out rows are fully rewritten by GEMM2 every call; only padding
    // rows need zeros (out float4-row token = i>>7).
    if (b_seq[i >> 7] == 0) out[i] = z;
    float4 v = ((const float4*)x)[i];
    t.b[0] = __float2bfloat16(v.x);
    t.b[1] = __float2bfloat16(v.y);
    t.b[2] = __float2bfloat16(v.z);
    t.b[3] = __float2bfloat16(v.w);
    ((uint2*)xb)[i] = t.u;
  }
}

__global__ void k_count_scan(const int4* __restrict__ b4,
                             int* __restrict__ hdr) {
  __shared__ int cnt[4];
  if (threadIdx.x < 4) cnt[threadIdx.x] = 0;
  __syncthreads();
  int c0 = 0, c1 = 0, c2 = 0, c3 = 0;
  for (int i = threadIdx.x; i < NTOK / 4; i += 1024) {
    int4 v = b4[i];
    c0 += (v.x == 1) + (v.y == 1) + (v.z == 1) + (v.w == 1);
    c1 += (v.x == 2) + (v.y == 2) + (v.z == 2) + (v.w == 2);
    c2 += (v.x == 3) + (v.y == 3) + (v.z == 3) + (v.w == 3);
    c3 += (v.x == 4) + (v.y == 4) + (v.z == 4) + (v.w == 4);
  }
  if (c0) atomicAdd(&cnt[0], c0);
  if (c1) atomicAdd(&cnt[1], c1);
  if (c2) atomicAdd(&cnt[2], c2);
  if (c3) atomicAdd(&cnt[3], c3);
  __syncthreads();
  if (threadIdx.x == 0) {
    int off = 0, b1 = 0, b2 = 0;
    for (int g = 0; g < 4; ++g) {
      int c = cnt[g];
      hdr[g] = c;
      hdr[8 + g] = off;
      hdr[4 + g] = off;   // cursor
      hdr[13 + g] = b1;
      hdr[18 + g] = b2;
      int mt = (c + 255) >> 8;   // 256-row m-tiles
      off += c;
      b1 += mt * (FDIM / 256);   // 8 n-tiles (BN=256)
      b2 += mt * (HDIM / 128);   // 4 n-tiles (BN=128)
    }
    hdr[12] = off; hdr[17] = b1; hdr[22] = b2;
  }
}

// LDS-aggregated fill: one global atomic per (block, expert).
__global__ void k_fill(const int* __restrict__ b_seq, int* __restrict__ hdr,
                       int* __restrict__ perm) {
  __shared__ int lcnt[4], base[4];
  const int tid = threadIdx.x;
  if (tid < 4) lcnt[tid] = 0;
  __syncthreads();
  const int i = blockIdx.x * 256 + tid;
  const int g = b_seq[i];
  int r = -1;
  if (g > 0) r = atomicAdd(&lcnt[g - 1], 1);
  __syncthreads();
  if (tid < 4) {
    int c = lcnt[tid];
    base[tid] = c ? atomicAdd(&hdr[4 + tid], c) : 0;
  }
  __syncthreads();
  if (g > 0) perm[base[g - 1] + r] = i;
}

// dst[g][c][r] = bf16(src[g][r][c]); grid (C/32, R/32, NEXP), block (32,8)
__global__ void k_transpose_cvt(const float* __restrict__ src,
                                __hip_bfloat16* __restrict__ dst, int R, int C) {
  __shared__ float tile[32][33];
  int g = blockIdx.z;
  const float* S = src + (size_t)g * R * C;
  __hip_bfloat16* D = dst + (size_t)g * R * C;
  int c0 = blockIdx.x << 5, r0 = blockIdx.y << 5;
  int tx = threadIdx.x, ty = threadIdx.y;
#pragma unroll
  for (int i = 0; i < 4; ++i) {
    int r = ty + i * 8;
    tile[r][tx] = S[(size_t)(r0 + r) * C + c0 + tx];
  }
  __syncthreads();
#pragma unroll
  for (int i = 0; i < 4; ++i) {
    int c = ty + i * 8;
    D[(size_t)(c0 + c) * R + r0 + tx] = __float2bfloat16(tile[tx][c]);
  }
}

__device__ __forceinline__ f32x4 mfma16(s16x8 a, s16x8 b, f32x4 c) {
  asm("v_mfma_f32_16x16x32_bf16 %0, %1, %2, %0" : "+v"(c) : "v"(a), "v"(b));
  return c;
}

__device__ __forceinline__ void gload16(const void* g, void* lds) {
  __builtin_amdgcn_global_load_lds(
      (const __attribute__((address_space(1))) unsigned int*)g,
      (__attribute__((address_space(3))) unsigned int*)lds, 16, 0, 0);
}

// Grouped GEMM, BM=256, BK=32, 512 threads = 8 waves (2m x 4n).
// LDS chunk-major: tile[kchunk][row][16B], kchunk = k/8. Staging dest is
// linear in tid (wave-uniform base + lane*16); fragment read at
// [lq][fragrow] is conflict-free (16B row stride spreads banks evenly).
// 2-phase: STAGE(next buf) -> COMPUTE(cur) -> vmcnt(0) -> s_barrier.
// MODE 1: 256x256 out; A = xb gathered via perm (K=512), B = W1t;
//         relu+bias; C staged in LDS (two 128-row halves) -> coalesced Hws.
// MODE 2: 256x128 out; A = Hws packed (K=2048), B = W2t; +bias; fp32 scatter.
template <int MODE>
__global__ __launch_bounds__(512, 2)
void k_gemm(const int* __restrict__ hdr, const int* __restrict__ perm,
            const __hip_bfloat16* __restrict__ Asrc,
            const __hip_bfloat16* __restrict__ Bsrc,
            const float* __restrict__ bias,
            const __hip_bfloat16* __restrict__ zp,
            __hip_bfloat16* __restrict__ Hout, float* __restrict__ Yout) {
  constexpr int BM  = 256;
  constexpr int BN  = (MODE == 1) ? 256 : 128;
  constexpr int K   = (MODE == 1) ? HDIM : FDIM;   // = LDA = LDB row length
  constexpr int NS  = K / 32;                      // K-steps (BK=32)
  constexpr int NT  = (MODE == 1) ? FDIM / 256 : HDIM / 128;
  constexpr int NF  = (MODE == 1) ? FDIM : HDIM;
  constexpr int NB  = BN / 64;                     // col frags per wave: 4|2
  constexpr int ABUF = BM * 32 * 2;                // 16KB per buffer
  constexpr int BBUF = BN * 32 * 2;                // 16KB | 8KB
  constexpr int CPX  = (MODE == 1) ? 68 : 34;      // grid/8 for XCD swizzle
  const int* tb = hdr + ((MODE == 1) ? 13 : 18);

  __shared__ char LDS[2 * ABUF + 2 * BBUF];        // 64KB | 48KB

  const int bid = blockIdx.x;
  const int w = (bid & 7) * CPX + (bid >> 3);      // XCD-contiguous tiles
  if (w >= tb[4]) return;

  const int tid = threadIdx.x, lane = tid & 63, wv = tid >> 6;
  const int wr = wv >> 2, wc = wv & 3;             // wave grid 2m x 4n
  const int l15 = lane & 15, lq = lane >> 4;

  int g = 0;
  while (tb[g + 1] <= w) ++g;
  const int local = w - tb[g];
  const int mt = local / NT, nt = local % NT;
  const int cnt = hdr[g], off = hdr[8 + g];
  int nrows = cnt - (mt << 8);
  nrows = nrows > 256 ? 256 : nrows;

  // staging sources: one row per thread, chunk-major dest linear in tid
  const int arow = tid & 255;
  const __hip_bfloat16* ap;
  if (MODE == 1) {
    if (arow < nrows) {
      const int tok = perm[off + (mt << 8) + arow];
      ap = Asrc + (size_t)tok * K + ((tid >> 8) << 3);
    } else {
      ap = zp + ((tid >> 8) << 3);   // zero slab (walks K, slab 8KB)
    }
  } else {
    // OOB rows read in-bounds garbage from Hws; results masked at store.
    ap = Asrc + (size_t)(off + (mt << 8) + arow) * K + ((tid >> 8) << 3);
  }
  const __hip_bfloat16* bp =
      (MODE == 1)
          ? Bsrc + ((size_t)g * NF + (nt << 8) + (tid & 255)) * K +
                ((tid >> 8) << 3)
          : Bsrc + ((size_t)g * NF + (nt << 7) + (tid & 127)) * K +
                ((tid >> 7) << 3);

  f32x4 acc[8][NB];
  const f32x4 fz = {0.f, 0.f, 0.f, 0.f};
#pragma unroll
  for (int m = 0; m < 8; ++m)
#pragma unroll
    for (int n = 0; n < NB; ++n) acc[m][n] = fz;

  auto STAGE = [&](int bf) {
    char* Ad = LDS + bf * ABUF + (wv << 10);
    char* Bd = LDS + 2 * ABUF + bf * BBUF + (wv << 10);
    gload16(ap, Ad);
    gload16(ap + 16, Ad + 8192);
    if constexpr (MODE == 1) {
      gload16(bp, Bd);
      gload16(bp + 16, Bd + 8192);
    } else {
      gload16(bp, Bd);
    }
    ap += 32;
    bp += 32;
  };
  auto COMPUTE = [&](int bf) {
    const char* Ab = LDS + bf * ABUF;
    const char* Bb = LDS + 2 * ABUF + bf * BBUF;
    s16x8 a[8], b[NB];
#pragma unroll
    for (int m = 0; m < 8; ++m) {
      const int row = (wr << 7) + (m << 4) + l15;
      a[m] = *(const s16x8*)(Ab + lq * (BM * 16) + row * 16);
    }
#pragma unroll
    for (int n = 0; n < NB; ++n) {
      const int row = wc * (BN / 4) + (n << 4) + l15;
      b[n] = *(const s16x8*)(Bb + lq * (BN * 16) + row * 16);
    }
#pragma unroll
    for (int m = 0; m < 8; ++m)
#pragma unroll
      for (int n = 0; n < NB; ++n)
        acc[m][n] = mfma16(a[m], b[n], acc[m][n]);
  };

  // r5-proven 2-phase skeleton
  STAGE(0);
  asm volatile("s_waitcnt vmcnt(0)" ::: "memory");
  __builtin_amdgcn_s_barrier();
  asm volatile("" ::: "memory");
  int bf = 0;
  for (int s = 0; s < NS; ++s) {
    if (s + 1 < NS) STAGE(bf ^ 1);
    COMPUTE(bf);
    asm volatile("s_waitcnt vmcnt(0)" ::: "memory");
    __builtin_amdgcn_s_barrier();
    asm volatile("" ::: "memory");
    bf ^= 1;
  }
  asm volatile("s_nop 7\ns_nop 7\ns_nop 7");  // MFMA->VALU hazard guard

  const int rq = lq << 2;
  if constexpr (MODE == 1) {
    // two 128-row half-passes through LDS, then coalesced 128B stores
#pragma unroll
    for (int h = 0; h < 2; ++h) {
      if (wr == h) {
#pragma unroll
        for (int n = 0; n < NB; ++n) {
          const int col = wc * 64 + (n << 4) + l15;
          const float bv = bias[g * NF + (nt << 8) + col];
#pragma unroll
          for (int m = 0; m < 8; ++m)
#pragma unroll
            for (int j = 0; j < 4; ++j) {
              const int r7 = (m << 4) + rq + j;   // 0..127
              float v = acc[m][n][j] + bv;
              v = v > 0.f ? v : 0.f;
              *(__hip_bfloat16*)(LDS + r7 * 512 + col * 2) =
                  __float2bfloat16(v);
            }
        }
      }
      __syncthreads();
      const int r7 = tid >> 2, qq = tid & 3;
      if ((h << 7) + r7 < nrows) {
        const char* src = LDS + r7 * 512 + qq * 128;
        char* dst =
            (char*)(Hout + ((size_t)(off + (mt << 8) + (h << 7) + r7) << 11) +
                    (nt << 8)) + qq * 128;
#pragma unroll
        for (int q = 0; q < 8; ++q)
          *(s16x8*)(dst + q * 16) = *(const s16x8*)(src + q * 16);
      }
      __syncthreads();
    }
  } else {
#pragma unroll
    for (int n = 0; n < NB; ++n) {
      const int ncol = (nt << 7) + wc * 32 + (n << 4) + l15;
      const float bv = bias[g * NF + ncol];
#pragma unroll
      for (int m = 0; m < 8; ++m)
#pragma unroll
        for (int j = 0; j < 4; ++j) {
          const int rl = (wr << 7) + (m << 4) + rq + j;
          if (rl < nrows) {
            const int tok = perm[off + (mt << 8) + rl];
            Yout[((size_t)tok << 9) + ncol] = acc[m][n][j] + bv;
          }
        }
    }
  }
}

extern "C" void kernel_launch(void* const* d_in, const int* in_sizes, int n_in,
                              void* d_out, int out_size, void* d_ws,
                              size_t ws_size, hipStream_t stream) {
  const float* x    = (const float*)d_in[0];
  const int* b_seq  = (const int*)d_in[1];
  const float* W1   = (const float*)d_in[2];
  const float* B1   = (const float*)d_in[3];
  const float* W2   = (const float*)d_in[4];
  const float* B2   = (const float*)d_in[5];
  float* out        = (float*)d_out;

  char* ws = (char*)d_ws;
  int* hdr  = (int*)ws;                         // 1 KB header
  int* perm = (int*)(ws + 1024);                // 64 KB
  __hip_bfloat16* zp = (__hip_bfloat16*)(ws + 66560);       // 8 KB zeros
  __hip_bfloat16* xb = zp + 4096;
  __hip_bfloat16* W1t = xb + (size_t)NTOK * HDIM;           // [4][2048][512]
  __hip_bfloat16* W2t = W1t + (size_t)NEXP * FDIM * HDIM;   // [4][512][2048]
  __hip_bfloat16* Hws = W2t + (size_t)NEXP * HDIM * FDIM;   // [16384][2048]

  const int n4 = NTOK * HDIM / 4;

  k_init_cvt<<<2048, 256, 0, stream>>>(x, b_seq, xb, (float4*)out, n4, hdr,
                                       (float4*)zp);
  k_count_scan<<<1, 1024, 0, stream>>>((const int4*)b_seq, hdr);
  k_fill<<<NTOK / 256, 256, 0, stream>>>(b_seq, hdr, perm);
  k_transpose_cvt<<<dim3(FDIM / 32, HDIM / 32, NEXP), dim3(32, 8), 0, stream>>>(
      W1, W1t, HDIM, FDIM);
  k_transpose_cvt<<<dim3(HDIM / 32, FDIM / 32, NEXP), dim3(32, 8), 0, stream>>>(
      W2, W2t, FDIM, HDIM);
  // grids: 544 = 8*68 >= max gemm1 tiles (67mt*8); 272 = 8*34 >= 67mt*4
  k_gemm<1><<<544, 512, 0, stream>>>(hdr, perm, xb, W1t, B1, zp, Hws, nullptr);
  k_gemm<2><<<272, 512, 0, stream>>>(hdr, perm, Hws, W2t, B2, zp, nullptr, out);
}

// Round 7
// 149.728 us; speedup vs baseline: 2.0095x; 2.0095x over previous
//
#include <hip/hip_runtime.h>
#include <hip/hip_bf16.h>

// ---------------------------------------------------------------------------
// BehaviorSpecificPFF: token-routed 4-expert FFN.
//   y[tok] = relu(x[tok] @ W1[g] + B1[g]) @ W2[g] + B2[g],  g = b_seq[tok]-1
//   b_seq==0 -> zeros.
// Round 7: COALESCED staging. Each global_load_lds wave-instruction now reads
// 8 rows x one full aligned 128B line (lane>>3 = row, lane&7 = chunk) instead
// of 32-64 scattered lines -> 4-8x fewer memory transactions per byte (the
// r3/r5/r6-invariant ~4.5 B/cy/block staging cap was transaction-rate bound).
// Structure reverted to the m97-proven skeleton: 128^2 tile, BK=64, single
// 32KB buffer + __syncthreads, 1 tile/block, ~4 blocks/CU co-residency.
// ---------------------------------------------------------------------------

typedef short s16x8 __attribute__((ext_vector_type(8)));
typedef float f32x4 __attribute__((ext_vector_type(4)));

#define NTOK   16384
#define HDIM   512
#define FDIM   2048
#define NEXP   4

// ---- header layout (ints) in ws ----
// [0..3] counts  [4..7] cursors  [8..12] token offsets ([12]=total)
// [13..17] gemm1 tile bases ([17]=total)  [18..22] gemm2 tile bases

__global__ void k_init_cvt(const float* __restrict__ x,
                           const int* __restrict__ b_seq,
                           __hip_bfloat16* __restrict__ xb,
                           float4* __restrict__ out, int n4,
                           int* __restrict__ hdr, float4* __restrict__ zp) {
  if (blockIdx.x == 0 && threadIdx.x < 32) hdr[threadIdx.x] = 0;
  float4 z; z.x = z.y = z.z = z.w = 0.f;
  int zb = (int)blockIdx.x - 1;
  if (zb >= 0 && zb < 2) zp[zb * 256 + threadIdx.x] = z;  // 8KB zero slab
  union { __hip_bfloat16 b[4]; uint2 u; } t;
  for (int i = blockIdx.x * blockDim.x + threadIdx.x; i < n4;
       i += gridDim.x * blockDim.x) {
    // non-pad out rows are fully rewritten by GEMM2 every call; only padding
    // rows need zeros (out float4-row token = i>>7).
    if (b_seq[i >> 7] == 0) out[i] = z;
    float4 v = ((const float4*)x)[i];
    t.b[0] = __float2bfloat16(v.x);
    t.b[1] = __float2bfloat16(v.y);
    t.b[2] = __float2bfloat16(v.z);
    t.b[3] = __float2bfloat16(v.w);
    ((uint2*)xb)[i] = t.u;
  }
}

__global__ void k_count_scan(const int4* __restrict__ b4,
                             int* __restrict__ hdr) {
  __shared__ int cnt[4];
  if (threadIdx.x < 4) cnt[threadIdx.x] = 0;
  __syncthreads();
  int c0 = 0, c1 = 0, c2 = 0, c3 = 0;
  for (int i = threadIdx.x; i < NTOK / 4; i += 1024) {
    int4 v = b4[i];
    c0 += (v.x == 1) + (v.y == 1) + (v.z == 1) + (v.w == 1);
    c1 += (v.x == 2) + (v.y == 2) + (v.z == 2) + (v.w == 2);
    c2 += (v.x == 3) + (v.y == 3) + (v.z == 3) + (v.w == 3);
    c3 += (v.x == 4) + (v.y == 4) + (v.z == 4) + (v.w == 4);
  }
  if (c0) atomicAdd(&cnt[0], c0);
  if (c1) atomicAdd(&cnt[1], c1);
  if (c2) atomicAdd(&cnt[2], c2);
  if (c3) atomicAdd(&cnt[3], c3);
  __syncthreads();
  if (threadIdx.x == 0) {
    int off = 0, b1 = 0, b2 = 0;
    for (int g = 0; g < 4; ++g) {
      int c = cnt[g];
      hdr[g] = c;
      hdr[8 + g] = off;
      hdr[4 + g] = off;   // cursor
      hdr[13 + g] = b1;
      hdr[18 + g] = b2;
      int mt = (c + 127) >> 7;   // 128-row m-tiles
      off += c;
      b1 += mt * (FDIM / 128);   // 16 n-tiles
      b2 += mt * (HDIM / 128);   // 4 n-tiles
    }
    hdr[12] = off; hdr[17] = b1; hdr[22] = b2;
  }
}

// LDS-aggregated fill: one global atomic per (block, expert).
__global__ void k_fill(const int* __restrict__ b_seq, int* __restrict__ hdr,
                       int* __restrict__ perm) {
  __shared__ int lcnt[4], base[4];
  const int tid = threadIdx.x;
  if (tid < 4) lcnt[tid] = 0;
  __syncthreads();
  const int i = blockIdx.x * 256 + tid;
  const int g = b_seq[i];
  int r = -1;
  if (g > 0) r = atomicAdd(&lcnt[g - 1], 1);
  __syncthreads();
  if (tid < 4) {
    int c = lcnt[tid];
    base[tid] = c ? atomicAdd(&hdr[4 + tid], c) : 0;
  }
  __syncthreads();
  if (g > 0) perm[base[g - 1] + r] = i;
}

// dst[g][c][r] = bf16(src[g][r][c]); grid (C/32, R/32, NEXP), block (32,8)
__global__ void k_transpose_cvt(const float* __restrict__ src,
                                __hip_bfloat16* __restrict__ dst, int R, int C) {
  __shared__ float tile[32][33];
  int g = blockIdx.z;
  const float* S = src + (size_t)g * R * C;
  __hip_bfloat16* D = dst + (size_t)g * R * C;
  int c0 = blockIdx.x << 5, r0 = blockIdx.y << 5;
  int tx = threadIdx.x, ty = threadIdx.y;
#pragma unroll
  for (int i = 0; i < 4; ++i) {
    int r = ty + i * 8;
    tile[r][tx] = S[(size_t)(r0 + r) * C + c0 + tx];
  }
  __syncthreads();
#pragma unroll
  for (int i = 0; i < 4; ++i) {
    int c = ty + i * 8;
    D[(size_t)(c0 + c) * R + r0 + tx] = __float2bfloat16(tile[tx][c]);
  }
}

__device__ __forceinline__ f32x4 mfma16(s16x8 a, s16x8 b, f32x4 c) {
  asm("v_mfma_f32_16x16x32_bf16 %0, %1, %2, %0" : "+v"(c) : "v"(a), "v"(b));
  return c;
}

__device__ __forceinline__ void gload16(const void* g, void* lds) {
  __builtin_amdgcn_global_load_lds(
      (const __attribute__((address_space(1))) unsigned int*)g,
      (__attribute__((address_space(3))) unsigned int*)lds, 16, 0, 0);
}

// Grouped GEMM, 128x128 tile, BK=64, 4 waves each computing [64,64].
// Staging (coalesced): instr i of wave wv covers rows wv*32+i*8 .. +7; lane
// l -> row wv*32+i*8+(l>>3), chunk l&7. Each wave-instruction = 8 aligned
// 128B lines. Source chunk pre-swizzled within its line (chunk ^= row&7);
// LDS dest linear [row][chunk]; fragment reads XOR the same swizzle.
// Skeleton: STAGE -> __syncthreads -> COMPUTE -> __syncthreads (m97 form).
// MODE 1: A = xb gathered via perm (K=512), B = W1t; relu+bias; C staged in
//         LDS (stride 272) -> coalesced 128B stores to packed Hws (bf16).
// MODE 2: A = Hws packed (K=2048), B = W2t; +bias; fp32 scatter to d_out.
template <int MODE>
__global__ __launch_bounds__(256, 2)
void k_gemm(const int* __restrict__ hdr, const int* __restrict__ perm,
            const __hip_bfloat16* __restrict__ Asrc,
            const __hip_bfloat16* __restrict__ Bsrc,
            const float* __restrict__ bias,
            const __hip_bfloat16* __restrict__ zp,
            __hip_bfloat16* __restrict__ Hout, float* __restrict__ Yout) {
  constexpr int K    = (MODE == 1) ? HDIM : FDIM;
  constexpr int NS   = K / 64;                    // K-steps
  constexpr int NT   = (MODE == 1) ? FDIM / 128 : HDIM / 128;
  constexpr int NF   = (MODE == 1) ? FDIM : HDIM;
  constexpr int CPX  = (MODE == 1) ? 264 : 66;    // grid/8 (worst-case tiles)
  constexpr int LDSZ = (MODE == 1) ? 34816 : 32768;  // 128*272 C-stage reuse
  const int* tb = hdr + ((MODE == 1) ? 13 : 18);

  __shared__ __align__(16) char LDS[LDSZ];
  char* As = LDS;            // 16KB: [128 rows][64 bf16]
  char* Bs = LDS + 16384;    // 16KB

  const int bid = blockIdx.x;
  const int w = (bid & 7) * CPX + (bid >> 3);     // XCD-contiguous tiles
  if (w >= tb[4]) return;

  const int tid = threadIdx.x, lane = tid & 63, wv = tid >> 6;
  const int wm = (wv >> 1) << 6, wn = (wv & 1) << 6;
  const int l15 = lane & 15, lq = lane >> 4;
  const int rsub = lane >> 3, c8 = lane & 7;      // staging: row-sub, chunk
  const int csw = (c8 ^ rsub) << 3;               // swizzled chunk (elems)

  int g = 0;
  while (tb[g + 1] <= w) ++g;
  const int local = w - tb[g];
  const int mt = local / NT, nt = local % NT;
  const int cnt = hdr[g], off = hdr[8 + g];
  int nrows = cnt - (mt << 7);
  nrows = nrows > 128 ? 128 : nrows;

  // per-instruction source pointers (advance 64 elems per K-step)
  const __hip_bfloat16* ap[4];
  const __hip_bfloat16* bp[4];
#pragma unroll
  for (int i = 0; i < 4; ++i) {
    const int r = (wv << 5) + (i << 3) + rsub;
    if (MODE == 1) {
      if (r < nrows) {
        const int tok = perm[off + (mt << 7) + r];
        ap[i] = Asrc + (size_t)tok * K + csw;
      } else {
        ap[i] = zp + csw;   // zero slab (walks K=512 -> 1KB < 8KB slab)
      }
    } else {
      // OOB rows read in-bounds finite garbage from Hws; masked at store.
      ap[i] = Asrc + (size_t)(off + (mt << 7) + r) * K + csw;
    }
    bp[i] = Bsrc + ((size_t)g * NF + (nt << 7) + r) * K + csw;
  }

  f32x4 acc[4][4];
  const f32x4 fz = {0.f, 0.f, 0.f, 0.f};
#pragma unroll
  for (int m = 0; m < 4; ++m)
#pragma unroll
    for (int n = 0; n < 4; ++n) acc[m][n] = fz;

  for (int s = 0; s < NS; ++s) {
#pragma unroll
    for (int i = 0; i < 4; ++i) {
      const int lo = (wv << 12) + (i << 10);      // wave-uniform LDS base
      gload16(ap[i], As + lo);
      gload16(bp[i], Bs + lo);
      ap[i] += 64;
      bp[i] += 64;
    }
    __syncthreads();                              // staging visible
#pragma unroll
    for (int kk = 0; kk < 2; ++kk) {
      const int kb = (kk << 6) + (lq << 4);
      s16x8 a[4], b[4];
#pragma unroll
      for (int m = 0; m < 4; ++m) {
        const int row = wm + (m << 4) + l15;
        a[m] = *(const s16x8*)(As + (row << 7) + (kb ^ ((row & 7) << 4)));
      }
#pragma unroll
      for (int n = 0; n < 4; ++n) {
        const int row = wn + (n << 4) + l15;
        b[n] = *(const s16x8*)(Bs + (row << 7) + (kb ^ ((row & 7) << 4)));
      }
#pragma unroll
      for (int m = 0; m < 4; ++m)
#pragma unroll
        for (int n = 0; n < 4; ++n)
          acc[m][n] = mfma16(a[m], b[n], acc[m][n]);
    }
    __syncthreads();                              // reads done before restage
  }
  asm volatile("s_nop 7\ns_nop 7\ns_nop 7");      // MFMA->VALU hazard guard

  const int rq = lq << 2;
  if constexpr (MODE == 1) {
    // stage relu(acc+bias) in LDS (stride 272 spreads banks), then
    // coalesced 128B half-row stores. LDS reused after final barrier.
#pragma unroll
    for (int n = 0; n < 4; ++n) {
      const int col = wn + (n << 4) + l15;
      const float bv = bias[g * NF + (nt << 7) + col];
#pragma unroll
      for (int m = 0; m < 4; ++m)
#pragma unroll
        for (int j = 0; j < 4; ++j) {
          const int row = wm + (m << 4) + rq + j;
          float v = acc[m][n][j] + bv;
          v = v > 0.f ? v : 0.f;
          *(__hip_bfloat16*)(LDS + row * 272 + col * 2) = __float2bfloat16(v);
        }
    }
    __syncthreads();
    const int r = tid >> 1, hf = tid & 1;
    if (r < nrows) {
      const char* src = LDS + r * 272 + hf * 128;
      char* dst = (char*)(Hout + ((size_t)(off + (mt << 7) + r) << 11) +
                          (nt << 7)) + hf * 128;
#pragma unroll
      for (int q = 0; q < 8; ++q)
        *(s16x8*)(dst + q * 16) = *(const s16x8*)(src + q * 16);
    }
  } else {
#pragma unroll
    for (int n = 0; n < 4; ++n) {
      const int ncol = (nt << 7) + wn + (n << 4) + l15;
      const float bv = bias[g * NF + ncol];
#pragma unroll
      for (int m = 0; m < 4; ++m)
#pragma unroll
        for (int j = 0; j < 4; ++j) {
          const int rl = wm + (m << 4) + rq + j;
          if (rl < nrows) {
            const int tok = perm[off + (mt << 7) + rl];
            Yout[((size_t)tok << 9) + ncol] = acc[m][n][j] + bv;
          }
        }
    }
  }
}

extern "C" void kernel_launch(void* const* d_in, const int* in_sizes, int n_in,
                              void* d_out, int out_size, void* d_ws,
                              size_t ws_size, hipStream_t stream) {
  const float* x    = (const float*)d_in[0];
  const int* b_seq  = (const int*)d_in[1];
  const float* W1   = (const float*)d_in[2];
  const float* B1   = (const float*)d_in[3];
  const float* W2   = (const float*)d_in[4];
  const float* B2   = (const float*)d_in[5];
  float* out        = (float*)d_out;

  char* ws = (char*)d_ws;
  int* hdr  = (int*)ws;                         // 1 KB header
  int* perm = (int*)(ws + 1024);                // 64 KB
  __hip_bfloat16* zp = (__hip_bfloat16*)(ws + 66560);       // 8 KB zeros
  __hip_bfloat16* xb = zp + 4096;
  __hip_bfloat16* W1t = xb + (size_t)NTOK * HDIM;           // [4][2048][512]
  __hip_bfloat16* W2t = W1t + (size_t)NEXP * FDIM * HDIM;   // [4][512][2048]
  __hip_bfloat16* Hws = W2t + (size_t)NEXP * HDIM * FDIM;   // [16384][2048]

  const int n4 = NTOK * HDIM / 4;

  k_init_cvt<<<2048, 256, 0, stream>>>(x, b_seq, xb, (float4*)out, n4, hdr,
                                       (float4*)zp);
  k_count_scan<<<1, 1024, 0, stream>>>((const int4*)b_seq, hdr);
  k_fill<<<NTOK / 256, 256, 0, stream>>>(b_seq, hdr, perm);
  k_transpose_cvt<<<dim3(FDIM / 32, HDIM / 32, NEXP), dim3(32, 8), 0, stream>>>(
      W1, W1t, HDIM, FDIM);
  k_transpose_cvt<<<dim3(HDIM / 32, FDIM / 32, NEXP), dim3(32, 8), 0, stream>>>(
      W2, W2t, FDIM, HDIM);
  // grids cover worst-case tile counts: <=132 m-tiles -> 2112 / 528
  k_gemm<1><<<2112, 256, 0, stream>>>(hdr, perm, xb, W1t, B1, zp, Hws, nullptr);
  k_gemm<2><<<528, 256, 0, stream>>>(hdr, perm, Hws, W2t, B2, zp, nullptr, out);
}